// Round 2
// baseline (495.003 us; speedup 1.0000x reference)
//
#include <hip/hip_runtime.h>
#include <math.h>

#define NG 5
#define NF 5
#define NR 5
#define NW 4
#define STEP 16          // 1 + NG + NF + NR
#define M_OTH 15         // NG + NF + NR
#define NB 60            // NW * M_OTH
#define L 512            // MAXLEN
#define FEAT 64
#define GAMMA 5.0f
#define BIGV 1e10f
#define SEGN 11          // STEP - NR
#define NSEG 44          // NW * SEGN
#define SEGD 32768       // MAXLEN * FEAT

// ---------------------------------------------------------------------------
// K1: pairwise squared distances, stored TRANSPOSED for the DTW kernel:
//   DT[b][j][i] = ||anchor_i - other_j||^2   (j = other index, i = anchor index)
// Achieved by swapping X/Y roles vs round 1. One block = 64x64 tile.
// ---------------------------------------------------------------------------
__global__ __launch_bounds__(256) void sqdist_kernel(const float* __restrict__ data,
                                                     float* __restrict__ DT) {
    int b = blockIdx.z;
    int w = b / M_OTH, m = b % M_OTH;
    const float* X = data + (size_t)(w * STEP + 1 + m) * L * FEAT;  // other  (DT rows)
    const float* Y = data + (size_t)(w * STEP) * L * FEAT;          // anchor (DT cols)
    int ti = blockIdx.y * 64;
    int tj = blockIdx.x * 64;

    __shared__ float Xs[64][68];
    __shared__ float Ys[64][68];

    int t = threadIdx.y * 16 + threadIdx.x;
    for (int k = 0; k < 4; ++k) {
        int idx = t + k * 256;
        int r = idx >> 4;
        int c = (idx & 15) * 4;
        float4 xv = *(const float4*)(X + (size_t)(ti + r) * FEAT + c);
        float4 yv = *(const float4*)(Y + (size_t)(tj + r) * FEAT + c);
        *(float4*)&Xs[r][c] = xv;
        *(float4*)&Ys[r][c] = yv;
    }
    __syncthreads();

    int i0 = threadIdx.y * 4;
    int j0 = threadIdx.x * 4;
    float acc[4][4] = {};
    for (int f = 0; f < FEAT; f += 4) {
        float4 xv[4], yv[4];
        #pragma unroll
        for (int a = 0; a < 4; ++a) xv[a] = *(float4*)&Xs[i0 + a][f];
        #pragma unroll
        for (int c = 0; c < 4; ++c) yv[c] = *(float4*)&Ys[j0 + c][f];
        #pragma unroll
        for (int a = 0; a < 4; ++a)
            #pragma unroll
            for (int c = 0; c < 4; ++c) {
                float d0 = xv[a].x - yv[c].x;
                float d1 = xv[a].y - yv[c].y;
                float d2 = xv[a].z - yv[c].z;
                float d3 = xv[a].w - yv[c].w;
                acc[a][c] += d0 * d0 + d1 * d1 + d2 * d2 + d3 * d3;
            }
    }
    float* Db = DT + (size_t)b * L * L;
    #pragma unroll
    for (int a = 0; a < 4; ++a)
        #pragma unroll
        for (int c = 0; c < 4; ++c)
            Db[(size_t)(ti + i0 + a) * L + (tj + j0 + c)] = fmaxf(acc[a][c], 0.0f);
}

// ---------------------------------------------------------------------------
// K2: soft-DTW, ONE WAVE per pair, barrier-free skewed pipeline.
// Lane l owns rows i = 8l+1 .. 8l+8 (in registers). At step t lane l processes
// column j = t - l + 1. Cross-lane dep (lane l-1 last row -> lane l first row)
// carried by __shfl_up; 2-deep history (a_in = R(8l, j), c_in = R(8l, j-1)).
// Early stop: rows > la and cols > lb never influence R(la, lb).
// ---------------------------------------------------------------------------
__global__ __launch_bounds__(64) void sdtw_kernel(const float* __restrict__ DT,
                                                  const int* __restrict__ lens,
                                                  float* __restrict__ res) {
    int b = blockIdx.x;
    int w = b / M_OTH, m = b % M_OTH;
    int la = lens[w * STEP];
    int lb = lens[w * STEP + 1 + m];
    int l = threadIdx.x;                        // 0..63
    const float* Db = DT + (size_t)b * L * L;   // DT[j][i] layout
    const float ig = 1.0f / GAMMA;

    float val[8];
    #pragma unroll
    for (int r = 0; r < 8; ++r) val[r] = BIGV;
    float a_in = BIGV;
    float c_in = (l == 0) ? 0.0f : BIGV;        // lane0 first cell: R(0,0)=0

    int lstar = (la - 1) >> 3;                  // lane holding row la
    int rstar = (la - 1) & 7;
    int tstop = lb + lstar;                     // last needed step is tstop-1
    float out = 0.0f;

    float4 Dc0 = {0, 0, 0, 0}, Dc1 = {0, 0, 0, 0};
    {
        int j0 = 1 - l;                          // column at t=0
        if (j0 >= 1 && j0 <= L) {
            const float* p = Db + (size_t)(j0 - 1) * L + 8 * l;
            Dc0 = *(const float4*)p;
            Dc1 = *(const float4*)(p + 4);
        }
    }

    for (int t = 0; t < tstop; ++t) {
        int j = t - l + 1;
        int jn = j + 1;
        float4 Dn0 = {0, 0, 0, 0}, Dn1 = {0, 0, 0, 0};
        bool vn = (jn >= 1) && (jn <= L) && (t + 1 < tstop);
        if (vn) {
            const float* p = Db + (size_t)(jn - 1) * L + 8 * l;
            Dn0 = *(const float4*)p;
            Dn1 = *(const float4*)(p + 4);
        }
        bool valid = (j >= 1) && (j <= L);
        if (valid) {
            float Dv[8] = {Dc0.x, Dc0.y, Dc0.z, Dc0.w, Dc1.x, Dc1.y, Dc1.z, Dc1.w};
            float ov[8];
            #pragma unroll
            for (int r = 0; r < 8; ++r) ov[r] = val[r];
            // b/c-dependent parts are independent of the serial a-chain: full ILP
            float m2[8], e2[8];
            #pragma unroll
            for (int r = 0; r < 8; ++r) {
                float bb = ov[r];                       // R(i, j-1)
                float cc = (r == 0) ? c_in : ov[r - 1]; // R(i-1, j-1)
                float mm = fminf(bb, cc);
                m2[r] = mm;
                e2[r] = __expf((mm - bb) * ig) + __expf((mm - cc) * ig);
            }
            // serial chain down the 8 rows
            float a = a_in;                             // R(i-1, j)
            #pragma unroll
            for (int r = 0; r < 8; ++r) {
                float mn = fminf(a, m2[r]);
                float s = __expf((mn - a) * ig) + e2[r] * __expf((mn - m2[r]) * ig);
                float nv = Dv[r] + mn - GAMMA * __logf(s);
                val[r] = nv;
                a = nv;
            }
            if (j == lb && l == lstar) out = val[rstar];
        }
        // pass last row up the pipeline (wave-uniform control flow here)
        float up = __shfl_up(val[7], 1);
        c_in = a_in;
        a_in = (l == 0) ? BIGV : up;
        Dc0 = Dn0;
        Dc1 = Dn1;
    }
    if (l == lstar) res[b] = out / (float)(la + lb);
}

// ---------------------------------------------------------------------------
// K3: Gram matrix of the 44 segment vectors (each 32768 floats).
// ---------------------------------------------------------------------------
__global__ __launch_bounds__(256) void gram_kernel(const float* __restrict__ data,
                                                   float* __restrict__ G) {
    int a = blockIdx.x, bb = blockIdx.y;
    if (bb < a) return;
    int wa = a / SEGN, sa = a % SEGN;
    int wb = bb / SEGN, sb = bb % SEGN;
    const float* va = data + (size_t)(wa * STEP + sa) * SEGD;
    const float* vb = data + (size_t)(wb * STEP + sb) * SEGD;
    int t = threadIdx.x;
    float acc = 0.f;
    for (int k = t * 4; k < SEGD; k += 256 * 4) {
        float4 x = *(const float4*)(va + k);
        float4 y = *(const float4*)(vb + k);
        acc += x.x * y.x + x.y * y.y + x.z * y.z + x.w * y.w;
    }
    __shared__ float red[256];
    red[t] = acc; __syncthreads();
    for (int s = 128; s > 0; s >>= 1) {
        if (t < s) red[t] += red[t + s];
        __syncthreads();
    }
    if (t == 0) { G[a * NSEG + bb] = red[0]; G[bb * NSEG + a] = red[0]; }
}

// ---------------------------------------------------------------------------
// K4: finalize — losses from the 60 DTW dists + 9 MMDs from the Gram.
// ---------------------------------------------------------------------------
__global__ __launch_bounds__(512) void finalize_kernel(const float* __restrict__ res,
                                                       const float* __restrict__ G,
                                                       float* __restrict__ out) {
    __shared__ float red[512];
    __shared__ float mmds[9];
    __shared__ float wloss[NW];
    __shared__ int   wnzr[NW];
    int t = threadIdx.x;

    if (t < NW) {
        int w = t;
        float dg[NG], dn[NF + NR];
        for (int g = 0; g < NG; ++g) dg[g] = res[w * M_OTH + g];
        for (int q = 0; q < NF + NR; ++q) dn[q] = res[w * M_OTH + NG + q];

        float sum_s = 0.f, sum_r = 0.f;
        int nzs = 0, nzr = 0;
        for (int g = 0; g < NG; ++g) {
            for (int f = 0; f < NF; ++f) {
                float v = dg[g] + 1.0f - dn[f];
                if (v > 0.f) { sum_s += v; nzs++; }
            }
            for (int r = 0; r < NR; ++r) {
                float v = dg[g] + 1.5f - dn[NF + r];
                if (v > 0.f) { sum_r += v; nzr++; }
            }
        }
        float ca = (dg[0] + dg[1] + dg[2] + dg[3] + dg[4]) / 5.0f;
        float cb = (dn[0] + dn[1] + dn[2] + dn[3]) * 0.25f;
        float intra = 0.f;
        for (int g = 0; g < NG; ++g) intra += dg[g] - ca;
        float inter = fmaxf(0.f, 1.0f - fabsf(ca - cb));
        float lv = (sum_s + sum_r) / (float)(nzs + nzr + 1);
        float bce = 0.f;
        for (int r = 0; r < NR; ++r) {
            float x = dn[NF + r] - dg[0];
            float ls = (x >= 0.f) ? -log1pf(expf(-x)) : (x - log1pf(expf(x)));
            bce += ls;
        }
        bce = -bce / 5.0f;
        wloss[w] = bce + lv + intra * 0.01f + inter * 0.01f;
        wnzr[w] = nzr;
    }
    __syncthreads();

    const int pi[9] = {0, 0, 0, 1, 1, 2, 2, 3, 3};
    const int pj[9] = {1, 2, 3, 2, 3, 1, 3, 1, 2};
    int pp = t / 22, qq = t % 22;

    for (int p = 0; p < 9; ++p) {
        int wi = pi[p], wj = pj[p];
        float myl2 = 0.f;
        if (t < 484) {
            int gp = (pp < 11) ? wi * SEGN + pp : wj * SEGN + (pp - 11);
            int gq = (qq < 11) ? wi * SEGN + qq : wj * SEGN + (qq - 11);
            float l2 = G[gp * NSEG + gp] + G[gq * NSEG + gq] - 2.f * G[gp * NSEG + gq];
            myl2 = fmaxf(l2, 0.f);
        }
        red[t] = myl2; __syncthreads();
        for (int s = 256; s > 0; s >>= 1) {
            if (t < s) red[t] += red[t + s];
            __syncthreads();
        }
        float bw = red[0] * (1.0f / 462.0f) * 0.25f;
        float kacc = 0.f;
        if (t < 484) {
            float sgn = ((pp < 11) == (qq < 11)) ? 1.f : -1.f;
            float x = -myl2 / bw;
            float e = expf(x) + expf(x * 0.5f) + expf(x * 0.25f) +
                      expf(x * 0.125f) + expf(x * 0.0625f);
            kacc = sgn * e;
        }
        __syncthreads();
        red[t] = kacc; __syncthreads();
        for (int s = 256; s > 0; s >>= 1) {
            if (t < s) red[t] += red[t + s];
            __syncthreads();
        }
        if (t == 0) mmds[p] = red[0] / 121.0f;
        __syncthreads();
    }

    if (t == 0) {
        float loss = 0.25f * (wloss[0] + wloss[1] + wloss[2] + wloss[3]);
        float mx = 0.f;
        for (int p = 0; p < 9; ++p) mx = fmaxf(mx, mmds[p]);
        out[0] = loss + 0.1f * mx;
        out[1] = (float)(wnzr[0] + wnzr[1] + wnzr[2] + wnzr[3]);
    }
}

// ---------------------------------------------------------------------------
extern "C" void kernel_launch(void* const* d_in, const int* in_sizes, int n_in,
                              void* d_out, int out_size, void* d_ws, size_t ws_size,
                              hipStream_t stream) {
    const float* data = (const float*)d_in[0];
    const int* lens = (const int*)d_in[1];

    float* DT  = (float*)d_ws;                               // 60*512*512 floats
    float* res = DT + (size_t)NB * L * L;                    // 60 floats
    float* G   = res + 64;                                   // 44*44 floats
    float* out = (float*)d_out;

    dim3 g1(8, 8, NB), b1(16, 16);
    sqdist_kernel<<<g1, b1, 0, stream>>>(data, DT);
    sdtw_kernel<<<NB, 64, 0, stream>>>(DT, lens, res);
    dim3 g3(NSEG, NSEG);
    gram_kernel<<<g3, 256, 0, stream>>>(data, G);
    finalize_kernel<<<1, 512, 0, stream>>>(res, G, out);
}

// Round 3
// 308.727 us; speedup vs baseline: 1.6034x; 1.6034x over previous
//
#include <hip/hip_runtime.h>
#include <math.h>

#define NG 5
#define NF 5
#define NR 5
#define NW 4
#define STEP 16          // 1 + NG + NF + NR
#define M_OTH 15         // NG + NF + NR
#define NB 60            // NW * M_OTH
#define L 512            // MAXLEN
#define FEAT 64
#define GAMMA 5.0f
#define BIGV 1e10f
#define SEGN 11          // STEP - NR
#define NSEG 44          // NW * SEGN
#define SEGD 32768       // MAXLEN * FEAT

#define C1   0.28853900817779268f   // 1/(GAMMA*ln2)
#define GLN2 3.4657359027997265f    // GAMMA*ln2
#define BIGS 2.8853900e9f           // BIGV*C1 (acts as +inf in scaled domain)

// ---------------------------------------------------------------------------
// K1: pairwise squared distances, stored TRANSPOSED and PRE-SCALED by C1:
//   DT[b][j][i] = C1 * ||anchor_i - other_j||^2
// ---------------------------------------------------------------------------
__global__ __launch_bounds__(256) void sqdist_kernel(const float* __restrict__ data,
                                                     float* __restrict__ DT) {
    int b = blockIdx.z;
    int w = b / M_OTH, m = b % M_OTH;
    const float* X = data + (size_t)(w * STEP + 1 + m) * L * FEAT;  // other  (DT rows)
    const float* Y = data + (size_t)(w * STEP) * L * FEAT;          // anchor (DT cols)
    int ti = blockIdx.y * 64;
    int tj = blockIdx.x * 64;

    __shared__ float Xs[64][68];
    __shared__ float Ys[64][68];

    int t = threadIdx.y * 16 + threadIdx.x;
    for (int k = 0; k < 4; ++k) {
        int idx = t + k * 256;
        int r = idx >> 4;
        int c = (idx & 15) * 4;
        float4 xv = *(const float4*)(X + (size_t)(ti + r) * FEAT + c);
        float4 yv = *(const float4*)(Y + (size_t)(tj + r) * FEAT + c);
        *(float4*)&Xs[r][c] = xv;
        *(float4*)&Ys[r][c] = yv;
    }
    __syncthreads();

    int i0 = threadIdx.y * 4;
    int j0 = threadIdx.x * 4;
    float acc[4][4] = {};
    for (int f = 0; f < FEAT; f += 4) {
        float4 xv[4], yv[4];
        #pragma unroll
        for (int a = 0; a < 4; ++a) xv[a] = *(float4*)&Xs[i0 + a][f];
        #pragma unroll
        for (int c = 0; c < 4; ++c) yv[c] = *(float4*)&Ys[j0 + c][f];
        #pragma unroll
        for (int a = 0; a < 4; ++a)
            #pragma unroll
            for (int c = 0; c < 4; ++c) {
                float d0 = xv[a].x - yv[c].x;
                float d1 = xv[a].y - yv[c].y;
                float d2 = xv[a].z - yv[c].z;
                float d3 = xv[a].w - yv[c].w;
                acc[a][c] += d0 * d0 + d1 * d1 + d2 * d2 + d3 * d3;
            }
    }
    float* Db = DT + (size_t)b * L * L;
    #pragma unroll
    for (int a = 0; a < 4; ++a)
        #pragma unroll
        for (int c = 0; c < 4; ++c)
            Db[(size_t)(ti + i0 + a) * L + (tj + j0 + c)] = fmaxf(acc[a][c], 0.0f) * C1;
}

// ---------------------------------------------------------------------------
// K2: soft-DTW, one wave per pair, barrier-free skewed pipeline.
// Scaled domain: V = R * C1, so each cell is exp2/log2 with no scaling muls in
// the serial chain. 4-deep statically-indexed prefetch ring; clamp-addressed
// loads (values for out-of-range columns are provably never consumed).
// ---------------------------------------------------------------------------
__global__ __launch_bounds__(64) void sdtw_kernel(const float* __restrict__ DT,
                                                  const int* __restrict__ lens,
                                                  float* __restrict__ res) {
    int b = blockIdx.x;
    int w = b / M_OTH, m = b % M_OTH;
    int la = lens[w * STEP];
    int lb = lens[w * STEP + 1 + m];
    int l = threadIdx.x;                        // 0..63, owns rows 8l+1..8l+8
    const float* Db = DT + (size_t)b * L * L;   // DT[j][i] layout, pre-scaled

    float V[8];
    #pragma unroll
    for (int r = 0; r < 8; ++r) V[r] = BIGS;
    float A_in = BIGS;                          // R(8l, j)   * C1
    float C_in = (l == 0) ? 0.0f : BIGS;        // R(8l, j-1) * C1

    int lstar = (la - 1) >> 3;                  // lane holding row la
    int rstar = (la - 1) & 7;                   // uniform (SGPR)
    int tstop = lb + lstar;
    int tpad = (tstop + 3) & ~3;
    float out = 0.0f;

    float4 sA[4], sB[4];                        // prefetch ring (static idx only)
    #pragma unroll
    for (int k = 0; k < 4; ++k) {
        int jn = k - l + 1;
        int jc = min(max(jn, 1), L);
        const float* p = Db + (size_t)(jc - 1) * L + 8 * l;
        sA[k] = *(const float4*)p;
        sB[k] = *(const float4*)(p + 4);
    }

    for (int t = 0; t < tpad; t += 4) {
        #pragma unroll
        for (int k = 0; k < 4; ++k) {
            int tt = t + k;
            int j = tt - l + 1;
            float Dc[8] = {sA[k].x, sA[k].y, sA[k].z, sA[k].w,
                           sB[k].x, sB[k].y, sB[k].z, sB[k].w};
            // prefetch step tt+4 into slot k (clamped address, no guard)
            {
                int jn = tt + 5 - l;
                int jc = min(max(jn, 1), L);
                const float* p = Db + (size_t)(jc - 1) * L + 8 * l;
                sA[k] = *(const float4*)p;
                sB[k] = *(const float4*)(p + 4);
            }
            // parallel (off-chain) part: pairwise min + exps of b/c terms
            float M2[8], E2[8];
            #pragma unroll
            for (int r = 0; r < 8; ++r) {
                float Bv = V[r];                         // R(i, j-1)*C1
                float Cv = (r == 0) ? C_in : V[r - 1];   // R(i-1, j-1)*C1
                float mm = fminf(Bv, Cv);
                M2[r] = mm;
                E2[r] = __builtin_amdgcn_exp2f(mm - Bv) +
                        __builtin_amdgcn_exp2f(mm - Cv);
            }
            // serial chain down the 8 rows
            float A = A_in;                              // R(i-1, j)*C1
            #pragma unroll
            for (int r = 0; r < 8; ++r) {
                float mn = fminf(A, M2[r]);
                float s = __builtin_amdgcn_exp2f(mn - A) +
                          E2[r] * __builtin_amdgcn_exp2f(mn - M2[r]);
                float nv = Dc[r] + (mn - __builtin_amdgcn_logf(s));
                V[r] = nv;
                A = nv;
                if (r == rstar) {                        // uniform compare
                    if (j == lb && l == lstar) out = nv;
                }
            }
            // pass last row up the pipeline
            float up = __shfl_up(V[7], 1);
            C_in = A_in;
            A_in = (l == 0) ? BIGS : up;
        }
    }
    if (l == lstar) res[b] = out * GLN2 / (float)(la + lb);
}

// ---------------------------------------------------------------------------
// K3: Gram matrix of the 44 segment vectors (each 32768 floats).
// ---------------------------------------------------------------------------
__global__ __launch_bounds__(256) void gram_kernel(const float* __restrict__ data,
                                                   float* __restrict__ G) {
    int a = blockIdx.x, bb = blockIdx.y;
    if (bb < a) return;
    int wa = a / SEGN, sa = a % SEGN;
    int wb = bb / SEGN, sb = bb % SEGN;
    const float* va = data + (size_t)(wa * STEP + sa) * SEGD;
    const float* vb = data + (size_t)(wb * STEP + sb) * SEGD;
    int t = threadIdx.x;
    float acc = 0.f;
    for (int k = t * 4; k < SEGD; k += 256 * 4) {
        float4 x = *(const float4*)(va + k);
        float4 y = *(const float4*)(vb + k);
        acc += x.x * y.x + x.y * y.y + x.z * y.z + x.w * y.w;
    }
    __shared__ float red[256];
    red[t] = acc; __syncthreads();
    for (int s = 128; s > 0; s >>= 1) {
        if (t < s) red[t] += red[t + s];
        __syncthreads();
    }
    if (t == 0) { G[a * NSEG + bb] = red[0]; G[bb * NSEG + a] = red[0]; }
}

// ---------------------------------------------------------------------------
// K4: finalize — losses from the 60 DTW dists + 9 MMDs from the Gram.
// ---------------------------------------------------------------------------
__global__ __launch_bounds__(512) void finalize_kernel(const float* __restrict__ res,
                                                       const float* __restrict__ G,
                                                       float* __restrict__ out) {
    __shared__ float red[512];
    __shared__ float mmds[9];
    __shared__ float wloss[NW];
    __shared__ int   wnzr[NW];
    int t = threadIdx.x;

    if (t < NW) {
        int w = t;
        float dg[NG], dn[NF + NR];
        for (int g = 0; g < NG; ++g) dg[g] = res[w * M_OTH + g];
        for (int q = 0; q < NF + NR; ++q) dn[q] = res[w * M_OTH + NG + q];

        float sum_s = 0.f, sum_r = 0.f;
        int nzs = 0, nzr = 0;
        for (int g = 0; g < NG; ++g) {
            for (int f = 0; f < NF; ++f) {
                float v = dg[g] + 1.0f - dn[f];
                if (v > 0.f) { sum_s += v; nzs++; }
            }
            for (int r = 0; r < NR; ++r) {
                float v = dg[g] + 1.5f - dn[NF + r];
                if (v > 0.f) { sum_r += v; nzr++; }
            }
        }
        float ca = (dg[0] + dg[1] + dg[2] + dg[3] + dg[4]) / 5.0f;
        float cb = (dn[0] + dn[1] + dn[2] + dn[3]) * 0.25f;
        float intra = 0.f;
        for (int g = 0; g < NG; ++g) intra += dg[g] - ca;
        float inter = fmaxf(0.f, 1.0f - fabsf(ca - cb));
        float lv = (sum_s + sum_r) / (float)(nzs + nzr + 1);
        float bce = 0.f;
        for (int r = 0; r < NR; ++r) {
            float x = dn[NF + r] - dg[0];
            float ls = (x >= 0.f) ? -log1pf(expf(-x)) : (x - log1pf(expf(x)));
            bce += ls;
        }
        bce = -bce / 5.0f;
        wloss[w] = bce + lv + intra * 0.01f + inter * 0.01f;
        wnzr[w] = nzr;
    }
    __syncthreads();

    const int pi[9] = {0, 0, 0, 1, 1, 2, 2, 3, 3};
    const int pj[9] = {1, 2, 3, 2, 3, 1, 3, 1, 2};
    int pp = t / 22, qq = t % 22;

    for (int p = 0; p < 9; ++p) {
        int wi = pi[p], wj = pj[p];
        float myl2 = 0.f;
        if (t < 484) {
            int gp = (pp < 11) ? wi * SEGN + pp : wj * SEGN + (pp - 11);
            int gq = (qq < 11) ? wi * SEGN + qq : wj * SEGN + (qq - 11);
            float l2 = G[gp * NSEG + gp] + G[gq * NSEG + gq] - 2.f * G[gp * NSEG + gq];
            myl2 = fmaxf(l2, 0.f);
        }
        red[t] = myl2; __syncthreads();
        for (int s = 256; s > 0; s >>= 1) {
            if (t < s) red[t] += red[t + s];
            __syncthreads();
        }
        float bw = red[0] * (1.0f / 462.0f) * 0.25f;
        float kacc = 0.f;
        if (t < 484) {
            float sgn = ((pp < 11) == (qq < 11)) ? 1.f : -1.f;
            float x = -myl2 / bw;
            float e = expf(x) + expf(x * 0.5f) + expf(x * 0.25f) +
                      expf(x * 0.125f) + expf(x * 0.0625f);
            kacc = sgn * e;
        }
        __syncthreads();
        red[t] = kacc; __syncthreads();
        for (int s = 256; s > 0; s >>= 1) {
            if (t < s) red[t] += red[t + s];
            __syncthreads();
        }
        if (t == 0) mmds[p] = red[0] / 121.0f;
        __syncthreads();
    }

    if (t == 0) {
        float loss = 0.25f * (wloss[0] + wloss[1] + wloss[2] + wloss[3]);
        float mx = 0.f;
        for (int p = 0; p < 9; ++p) mx = fmaxf(mx, mmds[p]);
        out[0] = loss + 0.1f * mx;
        out[1] = (float)(wnzr[0] + wnzr[1] + wnzr[2] + wnzr[3]);
    }
}

// ---------------------------------------------------------------------------
extern "C" void kernel_launch(void* const* d_in, const int* in_sizes, int n_in,
                              void* d_out, int out_size, void* d_ws, size_t ws_size,
                              hipStream_t stream) {
    const float* data = (const float*)d_in[0];
    const int* lens = (const int*)d_in[1];

    float* DT  = (float*)d_ws;                               // 60*512*512 floats
    float* res = DT + (size_t)NB * L * L;                    // 60 floats
    float* G   = res + 64;                                   // 44*44 floats
    float* out = (float*)d_out;

    dim3 g1(8, 8, NB), b1(16, 16);
    sqdist_kernel<<<g1, b1, 0, stream>>>(data, DT);
    sdtw_kernel<<<NB, 64, 0, stream>>>(DT, lens, res);
    dim3 g3(NSEG, NSEG);
    gram_kernel<<<g3, 256, 0, stream>>>(data, G);
    finalize_kernel<<<1, 512, 0, stream>>>(res, G, out);
}

// Round 4
// 227.828 us; speedup vs baseline: 2.1727x; 1.3551x over previous
//
#include <hip/hip_runtime.h>
#include <math.h>

#define NG 5
#define NF 5
#define NR 5
#define NW 4
#define STEP 16          // 1 + NG + NF + NR
#define M_OTH 15         // NG + NF + NR
#define NB 60            // NW * M_OTH
#define L 512            // MAXLEN
#define FEAT 64
#define GAMMA 5.0f
#define BIGV 1e10f
#define SEGN 11          // STEP - NR
#define NSEG 44          // NW * SEGN
#define SEGD 32768       // MAXLEN * FEAT

#define C1   0.28853900817779268f   // 1/(GAMMA*ln2)
#define GLN2 3.4657359027997265f    // GAMMA*ln2
#define BIGS 2.8853900e9f           // BIGV*C1 (acts as +inf in scaled domain)
#define BNDW 784                    // boundary slots (max step ~773)

// ---------------------------------------------------------------------------
// K1: pairwise squared distances, stored TRANSPOSED and PRE-SCALED by C1:
//   DT[b][j][i] = C1 * ||anchor_i - other_j||^2
// ---------------------------------------------------------------------------
__global__ __launch_bounds__(256) void sqdist_kernel(const float* __restrict__ data,
                                                     float* __restrict__ DT) {
    int b = blockIdx.z;
    int w = b / M_OTH, m = b % M_OTH;
    const float* X = data + (size_t)(w * STEP + 1 + m) * L * FEAT;  // other  (DT rows)
    const float* Y = data + (size_t)(w * STEP) * L * FEAT;          // anchor (DT cols)
    int ti = blockIdx.y * 64;
    int tj = blockIdx.x * 64;

    __shared__ float Xs[64][68];
    __shared__ float Ys[64][68];

    int t = threadIdx.y * 16 + threadIdx.x;
    for (int k = 0; k < 4; ++k) {
        int idx = t + k * 256;
        int r = idx >> 4;
        int c = (idx & 15) * 4;
        float4 xv = *(const float4*)(X + (size_t)(ti + r) * FEAT + c);
        float4 yv = *(const float4*)(Y + (size_t)(tj + r) * FEAT + c);
        *(float4*)&Xs[r][c] = xv;
        *(float4*)&Ys[r][c] = yv;
    }
    __syncthreads();

    int i0 = threadIdx.y * 4;
    int j0 = threadIdx.x * 4;
    float acc[4][4] = {};
    for (int f = 0; f < FEAT; f += 4) {
        float4 xv[4], yv[4];
        #pragma unroll
        for (int a = 0; a < 4; ++a) xv[a] = *(float4*)&Xs[i0 + a][f];
        #pragma unroll
        for (int c = 0; c < 4; ++c) yv[c] = *(float4*)&Ys[j0 + c][f];
        #pragma unroll
        for (int a = 0; a < 4; ++a)
            #pragma unroll
            for (int c = 0; c < 4; ++c) {
                float d0 = xv[a].x - yv[c].x;
                float d1 = xv[a].y - yv[c].y;
                float d2 = xv[a].z - yv[c].z;
                float d3 = xv[a].w - yv[c].w;
                acc[a][c] += d0 * d0 + d1 * d1 + d2 * d2 + d3 * d3;
            }
    }
    float* Db = DT + (size_t)b * L * L;
    #pragma unroll
    for (int a = 0; a < 4; ++a)
        #pragma unroll
        for (int c = 0; c < 4; ++c)
            Db[(size_t)(ti + i0 + a) * L + (tj + j0 + c)] = fmaxf(acc[a][c], 0.0f) * C1;
}

// ---------------------------------------------------------------------------
// K2: soft-DTW. 4 waves per block (1 per SIMD), R=2 rows per lane -> 512 rows.
// Lane G = tid (0..255) owns rows 2G+1, 2G+2; processes column j = t - G + 1
// at step t. Cross-lane dep via __shfl_up; cross-wave dep via write-once LDS
// slots initialized to NaN (value doubles as ready flag -> no fences/barriers).
// ---------------------------------------------------------------------------
__global__ __launch_bounds__(256) void sdtw_kernel(const float* __restrict__ DT,
                                                   const int* __restrict__ lens,
                                                   float* __restrict__ res) {
    int b = blockIdx.x;
    int w_ = b / M_OTH, m = b % M_OTH;
    int la = lens[w_ * STEP];
    int lb = lens[w_ * STEP + 1 + m];
    int tid = threadIdx.x;
    int W = tid >> 6;                  // wave 0..3
    int l = tid & 63;                  // lane in wave
    int G = tid;                       // global lane: rows 2G+1, 2G+2
    const float* Db = DT + (size_t)b * L * L;

    __shared__ float bnd[3][BNDW];
    for (int k = tid; k < 3 * BNDW; k += 256)
        ((float*)bnd)[k] = __int_as_float(0x7FC00000);   // NaN sentinel
    __syncthreads();                   // only barrier in the kernel

    int gstar = (la - 1) >> 1;         // lane holding row la
    int rstar = (la - 1) & 1;
    int tcap = lb + gstar - 1;         // step at which (la, lb) is computed
    if (64 * W > gstar) return;        // wave has no rows <= la

    int gmax = min(64 * W + 63, gstar);
    int t0 = 64 * W;
    int tend = lb + gmax - 1;

    float nv0 = BIGS, nv1 = BIGS;      // R(2G+1, j-1), R(2G+2, j-1), scaled
    float A0 = BIGS;                   // R(2G, j)
    float C0 = (G == 0) ? 0.0f : BIGS; // R(2G, j-1); R(0,0)=0 for lane 0
    float out = 0.0f;

    // 8-deep D prefetch ring (statically indexed via unroll)
    float2 ds_[8];
    int j = 1 - l;                     // column at step t0 (= t0 - G + 1)
    #pragma unroll
    for (int k = 0; k < 8; ++k) {
        int jc = min(max(j + k, 1), L);
        ds_[k] = *(const float2*)&Db[(size_t)(jc - 1) * L + 2 * G];
    }
    float ldv = 0.0f;
    if (W > 0) ldv = __hip_atomic_load(&bnd[W - 1][t0 - 1], __ATOMIC_RELAXED,
                                       __HIP_MEMORY_SCOPE_WORKGROUP);

    for (int t = t0; t <= tend; t += 8) {
        #pragma unroll
        for (int k = 0; k < 8; ++k) {
            int tt = t + k;
            // lane-0 boundary value: only needed while lane0's column <= lb
            bool need = (tt - 64 * W + 1) <= lb;
            if (W > 0 && need) {
                while (__builtin_isnan(ldv)) {            // uniform poll (rare)
                    __builtin_amdgcn_s_sleep(1);
                    ldv = __hip_atomic_load(&bnd[W - 1][tt - 1], __ATOMIC_RELAXED,
                                            __HIP_MEMORY_SCOPE_WORKGROUP);
                }
            }
            float lane0A = (W > 0 && need) ? ldv : BIGS;
            A0 = (l == 0) ? lane0A : A0;
            // speculative read for next step (write-once slots: always safe)
            float ldn = 0.0f;
            if (W > 0) ldn = __hip_atomic_load(&bnd[W - 1][tt], __ATOMIC_RELAXED,
                                               __HIP_MEMORY_SCOPE_WORKGROUP);
            float D0 = ds_[k].x, D1 = ds_[k].y;
            {   // prefetch step tt+8 into slot k (med3-clamped address)
                int jc = min(max(j + 8, 1), L);
                ds_[k] = *(const float2*)&Db[(size_t)(jc - 1) * L + 2 * G];
            }
            bool valid = (unsigned)(j - 1) < (unsigned)L;
            // cell 0: row 2G+1
            float mn0 = fminf(fminf(A0, nv0), C0);
            float s0 = __builtin_amdgcn_exp2f(mn0 - A0) +
                       __builtin_amdgcn_exp2f(mn0 - nv0) +
                       __builtin_amdgcn_exp2f(mn0 - C0);
            float t0v = D0 + (mn0 - __builtin_amdgcn_logf(s0));
            // cell 1: row 2G+2 (A = t0v, B = nv1, C = nv0)
            float mn1 = fminf(fminf(t0v, nv1), nv0);
            float s1 = __builtin_amdgcn_exp2f(mn1 - t0v) +
                       __builtin_amdgcn_exp2f(mn1 - nv1) +
                       __builtin_amdgcn_exp2f(mn1 - nv0);
            float t1v = D1 + (mn1 - __builtin_amdgcn_logf(s1));
            float nv0n = valid ? t0v : nv0;
            float nv1n = valid ? t1v : nv1;
            if (tt == tcap) {                             // uniform branch
                if (G == gstar) out = rstar ? t1v : t0v;
            }
            nv0 = nv0n;
            nv1 = nv1n;
            // producer: lane 63 publishes boundary row 128W+128
            if (W < 3 && l == 63)
                __hip_atomic_store(&bnd[W][tt], nv1, __ATOMIC_RELAXED,
                                   __HIP_MEMORY_SCOPE_WORKGROUP);
            // rotate cross-lane pipeline
            float up = __shfl_up(nv1, 1);
            C0 = A0;
            A0 = up;
            ldv = ldn;
            j += 1;
        }
    }
    if (G == gstar) res[b] = out * GLN2 / (float)(la + lb);
}

// ---------------------------------------------------------------------------
// K3: Gram matrix, 4x4-tiled: block (bx,by) computes segs [4bx..4bx+3] x
// [4by..4by+3]; reads 8 vectors instead of 2 per pair (4x fewer total bytes).
// ---------------------------------------------------------------------------
__global__ __launch_bounds__(256) void gram_kernel(const float* __restrict__ data,
                                                   float* __restrict__ Gm) {
    int bx = blockIdx.x, by = blockIdx.y;
    if (by < bx) return;
    int t = threadIdx.x;
    int lane = t & 63, wv = t >> 6;
    const float* pa[4];
    const float* pb[4];
    #pragma unroll
    for (int i = 0; i < 4; ++i) {
        int sa = bx * 4 + i;
        int sb = by * 4 + i;
        pa[i] = data + (size_t)((sa / SEGN) * STEP + (sa % SEGN)) * SEGD;
        pb[i] = data + (size_t)((sb / SEGN) * STEP + (sb % SEGN)) * SEGD;
    }
    float acc[16] = {};
    for (int d = t * 4; d < SEGD; d += 1024) {
        float4 ra[4], rb[4];
        #pragma unroll
        for (int i = 0; i < 4; ++i) ra[i] = *(const float4*)(pa[i] + d);
        #pragma unroll
        for (int i = 0; i < 4; ++i) rb[i] = *(const float4*)(pb[i] + d);
        #pragma unroll
        for (int i = 0; i < 4; ++i)
            #pragma unroll
            for (int jj = 0; jj < 4; ++jj)
                acc[i * 4 + jj] += ra[i].x * rb[jj].x + ra[i].y * rb[jj].y +
                                   ra[i].z * rb[jj].z + ra[i].w * rb[jj].w;
    }
    #pragma unroll
    for (int i = 0; i < 16; ++i)
        #pragma unroll
        for (int s = 32; s > 0; s >>= 1)
            acc[i] += __shfl_xor(acc[i], s);
    __shared__ float part[4][16];
    if (lane == 0)
        #pragma unroll
        for (int i = 0; i < 16; ++i) part[wv][i] = acc[i];
    __syncthreads();
    if (t < 16) {
        float s = part[0][t] + part[1][t] + part[2][t] + part[3][t];
        int a = bx * 4 + (t >> 2), c = by * 4 + (t & 3);
        Gm[a * NSEG + c] = s;
        Gm[c * NSEG + a] = s;
    }
}

// ---------------------------------------------------------------------------
// K4: finalize — losses from the 60 DTW dists + 9 MMDs from the Gram.
// ---------------------------------------------------------------------------
__global__ __launch_bounds__(512) void finalize_kernel(const float* __restrict__ res,
                                                       const float* __restrict__ G,
                                                       float* __restrict__ out) {
    __shared__ float red[512];
    __shared__ float mmds[9];
    __shared__ float wloss[NW];
    __shared__ int   wnzr[NW];
    int t = threadIdx.x;

    if (t < NW) {
        int w = t;
        float dg[NG], dn[NF + NR];
        for (int g = 0; g < NG; ++g) dg[g] = res[w * M_OTH + g];
        for (int q = 0; q < NF + NR; ++q) dn[q] = res[w * M_OTH + NG + q];

        float sum_s = 0.f, sum_r = 0.f;
        int nzs = 0, nzr = 0;
        for (int g = 0; g < NG; ++g) {
            for (int f = 0; f < NF; ++f) {
                float v = dg[g] + 1.0f - dn[f];
                if (v > 0.f) { sum_s += v; nzs++; }
            }
            for (int r = 0; r < NR; ++r) {
                float v = dg[g] + 1.5f - dn[NF + r];
                if (v > 0.f) { sum_r += v; nzr++; }
            }
        }
        float ca = (dg[0] + dg[1] + dg[2] + dg[3] + dg[4]) / 5.0f;
        float cb = (dn[0] + dn[1] + dn[2] + dn[3]) * 0.25f;
        float intra = 0.f;
        for (int g = 0; g < NG; ++g) intra += dg[g] - ca;
        float inter = fmaxf(0.f, 1.0f - fabsf(ca - cb));
        float lv = (sum_s + sum_r) / (float)(nzs + nzr + 1);
        float bce = 0.f;
        for (int r = 0; r < NR; ++r) {
            float x = dn[NF + r] - dg[0];
            float ls = (x >= 0.f) ? -log1pf(expf(-x)) : (x - log1pf(expf(x)));
            bce += ls;
        }
        bce = -bce / 5.0f;
        wloss[w] = bce + lv + intra * 0.01f + inter * 0.01f;
        wnzr[w] = nzr;
    }
    __syncthreads();

    const int pi[9] = {0, 0, 0, 1, 1, 2, 2, 3, 3};
    const int pj[9] = {1, 2, 3, 2, 3, 1, 3, 1, 2};
    int pp = t / 22, qq = t % 22;

    for (int p = 0; p < 9; ++p) {
        int wi = pi[p], wj = pj[p];
        float myl2 = 0.f;
        if (t < 484) {
            int gp = (pp < 11) ? wi * SEGN + pp : wj * SEGN + (pp - 11);
            int gq = (qq < 11) ? wi * SEGN + qq : wj * SEGN + (qq - 11);
            float l2 = G[gp * NSEG + gp] + G[gq * NSEG + gq] - 2.f * G[gp * NSEG + gq];
            myl2 = fmaxf(l2, 0.f);
        }
        red[t] = myl2; __syncthreads();
        for (int s = 256; s > 0; s >>= 1) {
            if (t < s) red[t] += red[t + s];
            __syncthreads();
        }
        float bw = red[0] * (1.0f / 462.0f) * 0.25f;
        float kacc = 0.f;
        if (t < 484) {
            float sgn = ((pp < 11) == (qq < 11)) ? 1.f : -1.f;
            float x = -myl2 / bw;
            float e = expf(x) + expf(x * 0.5f) + expf(x * 0.25f) +
                      expf(x * 0.125f) + expf(x * 0.0625f);
            kacc = sgn * e;
        }
        __syncthreads();
        red[t] = kacc; __syncthreads();
        for (int s = 256; s > 0; s >>= 1) {
            if (t < s) red[t] += red[t + s];
            __syncthreads();
        }
        if (t == 0) mmds[p] = red[0] / 121.0f;
        __syncthreads();
    }

    if (t == 0) {
        float loss = 0.25f * (wloss[0] + wloss[1] + wloss[2] + wloss[3]);
        float mx = 0.f;
        for (int p = 0; p < 9; ++p) mx = fmaxf(mx, mmds[p]);
        out[0] = loss + 0.1f * mx;
        out[1] = (float)(wnzr[0] + wnzr[1] + wnzr[2] + wnzr[3]);
    }
}

// ---------------------------------------------------------------------------
extern "C" void kernel_launch(void* const* d_in, const int* in_sizes, int n_in,
                              void* d_out, int out_size, void* d_ws, size_t ws_size,
                              hipStream_t stream) {
    const float* data = (const float*)d_in[0];
    const int* lens = (const int*)d_in[1];

    float* DT  = (float*)d_ws;                               // 60*512*512 floats
    float* res = DT + (size_t)NB * L * L;                    // 60 floats
    float* G   = res + 64;                                   // 44*44 floats
    float* out = (float*)d_out;

    dim3 g1(8, 8, NB), b1(16, 16);
    sqdist_kernel<<<g1, b1, 0, stream>>>(data, DT);
    sdtw_kernel<<<NB, 256, 0, stream>>>(DT, lens, res);
    dim3 g3(11, 11);
    gram_kernel<<<g3, 256, 0, stream>>>(data, G);
    finalize_kernel<<<1, 512, 0, stream>>>(res, G, out);
}

// Round 6
// 163.975 us; speedup vs baseline: 3.0188x; 1.3894x over previous
//
#include <hip/hip_runtime.h>
#include <math.h>

#define NG 5
#define NF 5
#define NR 5
#define NW 4
#define STEP 16          // 1 + NG + NF + NR
#define M_OTH 15         // NG + NF + NR
#define NB 60            // NW * M_OTH
#define L 512            // MAXLEN
#define FEAT 64
#define GAMMA 5.0f
#define SEGN 11          // STEP - NR
#define NSEG 44          // NW * SEGN
#define SEGD 32768       // MAXLEN * FEAT

#define C1   0.28853900817779268f   // 1/(GAMMA*ln2)
#define GLN2 3.4657359027997265f    // GAMMA*ln2
#define BIGS 2.8853900e9f           // 1e10*C1 (acts as +inf in scaled domain)
#define BNDW 792                    // boundary slots (16B-aligned rows, max idx 781)
#define GRAM_BLK0 60

// ---------------------------------------------------------------------------
// K1: pairwise sqdist, 128x128 tiles, norm-form (1 fma per cell-feat), stored
// in the DTW-skewed mod-512 layout, pre-scaled by C1:
//   DS[b][(jj + (ii>>1)) & 511][ii] = C1 * dist(anchor_ii, other_jj)
// (bijective per lane: for each (slot, ii-pair) exactly one jj maps there)
// ---------------------------------------------------------------------------
__global__ __launch_bounds__(256, 2) void sqdist_kernel(const float* __restrict__ data,
                                                        float* __restrict__ DS) {
    int b = blockIdx.z;
    int w = b / M_OTH, m = b % M_OTH;
    const float* X = data + (size_t)(w * STEP) * L * FEAT;            // anchor (i)
    const float* Y = data + (size_t)(w * STEP + 1 + m) * L * FEAT;    // other (j)
    int ti = blockIdx.y * 128;
    int tj = blockIdx.x * 128;

    __shared__ float Xs[128][68];
    __shared__ float Ys[128][68];
    __shared__ float nx[128], ny[128];

    int t = threadIdx.y * 16 + threadIdx.x;
    #pragma unroll
    for (int k = 0; k < 8; ++k) {
        int idx = t + k * 256;
        int r = idx >> 4, c = (idx & 15) * 4;
        *(float4*)&Xs[r][c] = *(const float4*)(X + (size_t)(ti + r) * FEAT + c);
        *(float4*)&Ys[r][c] = *(const float4*)(Y + (size_t)(tj + r) * FEAT + c);
    }
    __syncthreads();
    {   // row norms
        int r = t & 127;
        const float* row = (t < 128) ? Xs[r] : Ys[r];
        float s = 0.f;
        #pragma unroll
        for (int f = 0; f < 64; f += 4) {
            float4 v = *(const float4*)&row[f];
            s += v.x * v.x + v.y * v.y + v.z * v.z + v.w * v.w;
        }
        if (t < 128) nx[r] = s; else ny[r] = s;
    }
    __syncthreads();

    int tx = threadIdx.x, ty = threadIdx.y;   // ii = 16a+tx, jj = 16c+ty (strided)
    float acc[8][8] = {};
    for (int f = 0; f < 64; f += 4) {
        float4 xv[8], yv[8];
        #pragma unroll
        for (int a = 0; a < 8; ++a) xv[a] = *(const float4*)&Xs[16 * a + tx][f];
        #pragma unroll
        for (int c = 0; c < 8; ++c) yv[c] = *(const float4*)&Ys[16 * c + ty][f];
        #pragma unroll
        for (int a = 0; a < 8; ++a)
            #pragma unroll
            for (int c = 0; c < 8; ++c)
                acc[a][c] += xv[a].x * yv[c].x + xv[a].y * yv[c].y +
                             xv[a].z * yv[c].z + xv[a].w * yv[c].w;
    }
    #pragma unroll
    for (int a = 0; a < 8; ++a) {
        int ii = ti + 16 * a + tx;
        float xn = nx[16 * a + tx];
        #pragma unroll
        for (int c = 0; c < 8; ++c) {
            int jj = tj + 16 * c + ty;
            float d = xn + ny[16 * c + ty] - 2.0f * acc[a][c];
            size_t idx = ((size_t)b * 512 + ((jj + (ii >> 1)) & 511)) * 512 + ii;
            DS[idx] = fmaxf(d, 0.0f) * C1;
        }
    }
}

// up[l] = x[l-1] via DPP (no LDS): row_shr:1 + row_bcast15 fixes lanes 16/32/48.
__device__ __forceinline__ float dpp_shift_up1(float x) {
    int xi = __float_as_int(x);
    int sh  = __builtin_amdgcn_update_dpp(xi, xi, 0x111, 0xF, 0xF, false); // row_shr:1
    int b15 = __builtin_amdgcn_update_dpp(xi, xi, 0x142, 0xF, 0xF, false); // row_bcast15
    int lane = (int)(threadIdx.x & 63);
    int r = ((lane & 15) == 0) ? b15 : sh;
    return __int_as_float(r);
}

// ---------------------------------------------------------------------------
// gram tile body (blocks 60..125): 4x4 segment tile, flat id -> (bx<=by)
// ---------------------------------------------------------------------------
__device__ void gram_body(const float* __restrict__ data, float* __restrict__ Gm, int f) {
    int bx = 0, rem = f;
    for (int q = 0; q < 11; ++q) { int c = 11 - q; if (rem < c) { bx = q; break; } rem -= c; }
    int by = bx + rem;
    int t = threadIdx.x;
    int lane = t & 63, wv = t >> 6;
    const float* pa[4];
    const float* pb[4];
    #pragma unroll
    for (int i = 0; i < 4; ++i) {
        int sa = bx * 4 + i;
        int sb = by * 4 + i;
        pa[i] = data + (size_t)((sa / SEGN) * STEP + (sa % SEGN)) * SEGD;
        pb[i] = data + (size_t)((sb / SEGN) * STEP + (sb % SEGN)) * SEGD;
    }
    float acc[16] = {};
    for (int d = t * 4; d < SEGD; d += 1024) {
        float4 ra[4], rb[4];
        #pragma unroll
        for (int i = 0; i < 4; ++i) ra[i] = *(const float4*)(pa[i] + d);
        #pragma unroll
        for (int i = 0; i < 4; ++i) rb[i] = *(const float4*)(pb[i] + d);
        #pragma unroll
        for (int i = 0; i < 4; ++i)
            #pragma unroll
            for (int jj = 0; jj < 4; ++jj)
                acc[i * 4 + jj] += ra[i].x * rb[jj].x + ra[i].y * rb[jj].y +
                                   ra[i].z * rb[jj].z + ra[i].w * rb[jj].w;
    }
    #pragma unroll
    for (int i = 0; i < 16; ++i)
        #pragma unroll
        for (int s = 32; s > 0; s >>= 1)
            acc[i] += __shfl_xor(acc[i], s);
    __shared__ float part[4][16];
    if (lane == 0)
        #pragma unroll
        for (int i = 0; i < 16; ++i) part[wv][i] = acc[i];
    __syncthreads();
    if (t < 16) {
        float s = part[0][t] + part[1][t] + part[2][t] + part[3][t];
        int a = bx * 4 + (t >> 2), c = by * 4 + (t & 3);
        Gm[a * NSEG + c] = s;
        Gm[c * NSEG + a] = s;
    }
}

// ---------------------------------------------------------------------------
// K2: soft-DTW (blocks 0..59) + gram (blocks 60..125).
// DTW: 4 waves, lane G owns rows 2G+1,2G+2; col j = tt-G+1 at step tt.
// Cross-lane via DPP; cross-wave via write-once NaN-sentinel LDS slots,
// consumed in 8-slot chunks with speculative read + register NaN-check.
// D read coalesced via the mod-512 skewed layout (512B per wave per step).
// ---------------------------------------------------------------------------
__global__ __launch_bounds__(256) void dtw_gram_kernel(const float* __restrict__ DS,
                                                       const int* __restrict__ lens,
                                                       const float* __restrict__ data,
                                                       float* __restrict__ res,
                                                       float* __restrict__ Gm) {
    int blk = blockIdx.x;
    if (blk >= GRAM_BLK0) { gram_body(data, Gm, blk - GRAM_BLK0); return; }

    int b = blk;
    int w_ = b / M_OTH, m = b % M_OTH;
    int la = lens[w_ * STEP];
    int lb = lens[w_ * STEP + 1 + m];
    int tid = threadIdx.x;
    int W = tid >> 6, l = tid & 63, G = tid;
    const float* Db = DS + (size_t)b * 512 * 512;

    __shared__ float bnd[3][BNDW];
    for (int k = tid; k < 3 * BNDW; k += 256)
        ((float*)bnd)[k] = __int_as_float(0x7FC00000);   // NaN sentinel
    __syncthreads();                                     // only barrier (DTW path)

    int gstar = (la - 1) >> 1;
    int rstar = (la - 1) & 1;
    int tcap = lb + gstar - 1;
    if (64 * W > gstar) return;
    int gmax = min(64 * W + 63, gstar);
    int t0 = 64 * W;
    int tend = lb + gmax - 1;
    int needmax = lb + 64 * W - 1;     // last step needing a boundary (W>0)
    bool pub = (W < 3);

    float nv0 = BIGS, nv1 = BIGS;      // R(2G+1, j-1), R(2G+2, j-1)  (scaled)
    float A0 = BIGS;                   // R(2G, j)
    float C0 = (G == 0) ? 0.0f : BIGS; // R(2G, j-1); R(0,0)=0
    float out = 0.0f;

    float2 ring[8];                    // D prefetch ring (static idx)
    #pragma unroll
    for (int k = 0; k < 8; ++k)
        ring[k] = *(const float2*)&Db[(size_t)((t0 + k) & 511) * 512 + 2 * G];
    float ch[8];                       // boundary chunk (static idx)
    #pragma unroll
    for (int k = 0; k < 8; ++k) ch[k] = __int_as_float(0x7FC00000);

    int j = 1 - l;                     // column at step t0: t0 - G + 1 = 1 - l
    const float* bsrc = (W > 0) ? bnd[W - 1] : bnd[0];

    for (int t = t0; t <= tend; t += 8) {
        if (W > 0 && t <= needmax) {                     // validate chunk
            int lastIdx = min(t + 7, needmax);
            bool full = (t + 7 <= needmax);
            bool ok = full && !__builtin_isnan(ch[3]) && !__builtin_isnan(ch[7]);
            if (!ok) {
                float v = __hip_atomic_load(&bsrc[lastIdx], __ATOMIC_RELAXED,
                                            __HIP_MEMORY_SCOPE_WORKGROUP);
                while (__builtin_isnan(v)) {
                    __builtin_amdgcn_s_sleep(2);
                    v = __hip_atomic_load(&bsrc[lastIdx], __ATOMIC_RELAXED,
                                          __HIP_MEMORY_SCOPE_WORKGROUP);
                }
                __builtin_amdgcn_fence(__ATOMIC_ACQUIRE, "workgroup");
                #pragma unroll
                for (int k = 0; k < 8; ++k)
                    ch[k] = __hip_atomic_load(&bsrc[t + k], __ATOMIC_RELAXED,
                                              __HIP_MEMORY_SCOPE_WORKGROUP);
            }
        }
        #pragma unroll
        for (int k = 0; k < 8; ++k) {
            int tt = t + k;
            float l0 = BIGS;
            if (W > 0) l0 = (tt <= needmax) ? ch[k] : BIGS;
            A0 = (l == 0) ? l0 : A0;
            float D0 = ring[k].x, D1 = ring[k].y;
            ring[k] = *(const float2*)&Db[(size_t)((tt + 8) & 511) * 512 + 2 * G];
            // off-chain: E2 = 1 + exp2(min-max) for the (B,C) pairs
            float m2a = fminf(nv0, C0), mxa = fmaxf(nv0, C0);
            float E2a = 1.0f + __builtin_amdgcn_exp2f(m2a - mxa);
            float m2b = fminf(nv1, nv0), mxb = fmaxf(nv1, nv0);
            float E2b = 1.0f + __builtin_amdgcn_exp2f(m2b - mxb);
            // serial chain (2 cells)
            float mn0 = fminf(A0, m2a);
            float s0 = __builtin_amdgcn_exp2f(mn0 - A0) +
                       E2a * __builtin_amdgcn_exp2f(mn0 - m2a);
            float t0v = D0 + (mn0 - __builtin_amdgcn_logf(s0));
            float mn1 = fminf(t0v, m2b);
            float s1 = __builtin_amdgcn_exp2f(mn1 - t0v) +
                       E2b * __builtin_amdgcn_exp2f(mn1 - m2b);
            float t1v = D1 + (mn1 - __builtin_amdgcn_logf(s1));
            bool valid = (unsigned)(j - 1) < (unsigned)L;
            nv0 = valid ? t0v : nv0;
            nv1 = valid ? t1v : nv1;
            if (tt == tcap) { if (G == gstar) out = rstar ? nv1 : nv0; }
            float up = dpp_shift_up1(nv1);               // VALU-only lane shift
            if (pub && l == 63)
                __hip_atomic_store(&bnd[W][tt + 1], nv1, __ATOMIC_RELAXED,
                                   __HIP_MEMORY_SCOPE_WORKGROUP);
            C0 = A0;
            A0 = up;                                     // lane0 overridden next step
            j += 1;
        }
        if (W > 0) {                                     // speculative next chunk
            float4 ca = *(const float4*)&bsrc[t + 8];
            float4 cb = *(const float4*)&bsrc[t + 12];
            ch[0] = ca.x; ch[1] = ca.y; ch[2] = ca.z; ch[3] = ca.w;
            ch[4] = cb.x; ch[5] = cb.y; ch[6] = cb.z; ch[7] = cb.w;
        }
    }
    if (G == gstar) res[b] = out * GLN2 / (float)(la + lb);
}

// ---------------------------------------------------------------------------
// K3: finalize — losses + 9 MMDs, wave-shuffle reductions (5 barriers total).
// ---------------------------------------------------------------------------
__global__ __launch_bounds__(512) void finalize_kernel(const float* __restrict__ res,
                                                       const float* __restrict__ G,
                                                       float* __restrict__ out) {
    __shared__ float wpart[9][8];
    __shared__ float bws[9];
    __shared__ float mmds[9];
    __shared__ float wloss[NW];
    __shared__ int   wnzr[NW];
    int t = threadIdx.x, lane = t & 63, wv = t >> 6;

    if (t < NW) {
        int w = t;
        float dg[NG], dn[NF + NR];
        for (int g = 0; g < NG; ++g) dg[g] = res[w * M_OTH + g];
        for (int q = 0; q < NF + NR; ++q) dn[q] = res[w * M_OTH + NG + q];
        float sum_s = 0.f, sum_r = 0.f;
        int nzs = 0, nzr = 0;
        for (int g = 0; g < NG; ++g) {
            for (int f = 0; f < NF; ++f) {
                float v = dg[g] + 1.0f - dn[f];
                if (v > 0.f) { sum_s += v; nzs++; }
            }
            for (int r = 0; r < NR; ++r) {
                float v = dg[g] + 1.5f - dn[NF + r];
                if (v > 0.f) { sum_r += v; nzr++; }
            }
        }
        float ca = (dg[0] + dg[1] + dg[2] + dg[3] + dg[4]) / 5.0f;
        float cb = (dn[0] + dn[1] + dn[2] + dn[3]) * 0.25f;
        float intra = 0.f;
        for (int g = 0; g < NG; ++g) intra += dg[g] - ca;
        float inter = fmaxf(0.f, 1.0f - fabsf(ca - cb));
        float lv = (sum_s + sum_r) / (float)(nzs + nzr + 1);
        float bce = 0.f;
        for (int r = 0; r < NR; ++r) {
            float x = dn[NF + r] - dg[0];
            float ls = (x >= 0.f) ? -log1pf(expf(-x)) : (x - log1pf(expf(x)));
            bce += ls;
        }
        bce = -bce / 5.0f;
        wloss[w] = bce + lv + intra * 0.01f + inter * 0.01f;
        wnzr[w] = nzr;
    }

    const int pi[9] = {0, 0, 0, 1, 1, 2, 2, 3, 3};
    const int pj[9] = {1, 2, 3, 2, 3, 1, 3, 1, 2};
    int pp = t / 22, qq = t % 22;
    bool act = t < 484;
    float l2v[9];
    #pragma unroll
    for (int p = 0; p < 9; ++p) {
        float v = 0.f;
        if (act) {
            int wi = pi[p], wj = pj[p];
            int gp = (pp < 11) ? wi * SEGN + pp : wj * SEGN + (pp - 11);
            int gq = (qq < 11) ? wi * SEGN + qq : wj * SEGN + (qq - 11);
            v = fmaxf(G[gp * NSEG + gp] + G[gq * NSEG + gq] - 2.f * G[gp * NSEG + gq], 0.f);
        }
        l2v[p] = v;
    }
    #pragma unroll
    for (int p = 0; p < 9; ++p) {
        float r = l2v[p];
        #pragma unroll
        for (int s = 32; s > 0; s >>= 1) r += __shfl_xor(r, s);
        if (lane == 0) wpart[p][wv] = r;
    }
    __syncthreads();
    if (t < 9) {
        float s = 0.f;
        #pragma unroll
        for (int k = 0; k < 8; ++k) s += wpart[t][k];
        bws[t] = s * (1.0f / 462.0f) * 0.25f;
    }
    __syncthreads();
    float sgn = ((pp < 11) == (qq < 11)) ? 1.f : -1.f;
    #pragma unroll
    for (int p = 0; p < 9; ++p) {
        float kv = 0.f;
        if (act) {
            float x = -l2v[p] / bws[p];
            kv = sgn * (__expf(x) + __expf(x * 0.5f) + __expf(x * 0.25f) +
                        __expf(x * 0.125f) + __expf(x * 0.0625f));
        }
        #pragma unroll
        for (int s = 32; s > 0; s >>= 1) kv += __shfl_xor(kv, s);
        if (lane == 0) wpart[p][wv] = kv;
    }
    __syncthreads();
    if (t < 9) {
        float s = 0.f;
        #pragma unroll
        for (int k = 0; k < 8; ++k) s += wpart[t][k];
        mmds[t] = s / 121.0f;
    }
    __syncthreads();
    if (t == 0) {
        float loss = 0.25f * (wloss[0] + wloss[1] + wloss[2] + wloss[3]);
        float mx = 0.f;
        for (int p = 0; p < 9; ++p) mx = fmaxf(mx, mmds[p]);
        out[0] = loss + 0.1f * mx;
        out[1] = (float)(wnzr[0] + wnzr[1] + wnzr[2] + wnzr[3]);
    }
}

// ---------------------------------------------------------------------------
extern "C" void kernel_launch(void* const* d_in, const int* in_sizes, int n_in,
                              void* d_out, int out_size, void* d_ws, size_t ws_size,
                              hipStream_t stream) {
    const float* data = (const float*)d_in[0];
    const int* lens = (const int*)d_in[1];

    float* DS  = (float*)d_ws;                               // 60*512*512 floats
    float* res = DS + (size_t)NB * 512 * 512;                // 60 floats
    float* G   = res + 64;                                   // 44*44 floats
    float* out = (float*)d_out;

    dim3 g1(4, 4, NB), b1(16, 16);
    sqdist_kernel<<<g1, b1, 0, stream>>>(data, DS);
    dtw_gram_kernel<<<GRAM_BLK0 + 66, 256, 0, stream>>>(DS, lens, data, res, G);
    finalize_kernel<<<1, 512, 0, stream>>>(res, G, out);
}